// Round 8
// baseline (40.605 us; speedup 1.0000x reference)
//
#include <hip/hip_runtime.h>
#include <hip/hip_bf16.h>

#define BB 4
#define TT 2048
#define DD 128
#define CHK 64
#define NCHK 32            // TT/CHK
#define NCHKS (BB*NCHK)    // 128 chunks total

typedef __attribute__((ext_vector_type(8))) short  bf16x8;
typedef __attribute__((ext_vector_type(4))) float  f32x4;

#define MFMA(a,b,c) __builtin_amdgcn_mfma_f32_16x16x32_bf16(a, b, c, 0, 0, 0)

__device__ __forceinline__ short f2b(float f) {
    union { float f; unsigned u; } x; x.f = f;
    unsigned r = x.u + 0x7fffu + ((x.u >> 16) & 1u);   // RNE
    return (short)(r >> 16);
}
__device__ __forceinline__ float b2f(short s) {
    union { unsigned u; float f; } x; x.u = ((unsigned)(unsigned short)s) << 16;
    return x.f;
}
__device__ __forceinline__ bf16x8 cvt8(const float* p) {
    float4 a = *(const float4*)p, b = *(const float4*)(p + 4);
    bf16x8 r;
    r[0]=f2b(a.x); r[1]=f2b(a.y); r[2]=f2b(a.z); r[3]=f2b(a.w);
    r[4]=f2b(b.x); r[5]=f2b(b.y); r[6]=f2b(b.z); r[7]=f2b(b.w);
    return r;
}

// ---------------------------------------------------------------------------
// K1: block (c, h): phi(k) full -> KfT (for S-GEMM);
//     h==0: stage Kf row-major -> global, z_c.
//     h==1: phi(q) full, stage Qf row-major -> global.
//     vT half -> global; S_half = Kf^T V_half -> Ss_g bf16 [c][e][d].
// grid 256 x 256. LDS ~79.9 KB -> 2 blocks/CU.
// ---------------------------------------------------------------------------
__global__ __launch_bounds__(256) void k1_chunk(const float* __restrict__ q,
                                                const float* __restrict__ kin,
                                                const float* __restrict__ vin,
                                                const float* __restrict__ W,
                                                const float* __restrict__ bias,
                                                short* __restrict__ Ss_g,
                                                float* __restrict__ zc_g,
                                                short* __restrict__ vT_g,
                                                short* __restrict__ Qf_g,
                                                short* __restrict__ Kf_g) {
    int c = blockIdx.x >> 1, h = blockIdx.x & 1;
    const float* qc = q   + (size_t)c * CHK * DD;
    const float* kc = kin + (size_t)c * CHK * DD;
    const float* vc = vin + (size_t)c * CHK * DD;

    __shared__ __align__(16) short Wl  [DD][DD + 8];    // 34816 B
    __shared__ __align__(16) short KfT [DD][CHK + 8];   // 18432 B  (KfT[d][t])
    __shared__ __align__(16) short vT  [CHK][CHK + 8];  // 9216 B   (vT[e_local][t])
    __shared__ __align__(16) short stage[CHK][DD + 8];  // 17408 B  Qf/Kf rowmajor, then Ss bf16

    int tid = threadIdx.x, lane = tid & 63, w = tid >> 6;
    int l15 = lane & 15, l4 = lane >> 4;
    const f32x4 z4 = {0.f, 0.f, 0.f, 0.f};

    // prefetch A-fragments (k always; q on h==1)
    bf16x8 afk[4], afq[4];
    {
        int row = 16 * w + l15;
        #pragma unroll
        for (int kk = 0; kk < 4; ++kk) afk[kk] = cvt8(kc + row * DD + kk * 32 + l4 * 8);
        if (h) {
            #pragma unroll
            for (int kk = 0; kk < 4; ++kk) afq[kk] = cvt8(qc + row * DD + kk * 32 + l4 * 8);
        }
    }
    // W fp32 -> LDS bf16 (padded rows)
    #pragma unroll
    for (int it = 0; it < 16; ++it) {
        int i = tid + it * 256;               // 4096 float4s
        int row = i >> 5, c4 = (i & 31) * 4;
        float4 v = *(const float4*)(W + (size_t)row * DD + c4);
        unsigned lo = (unsigned short)f2b(v.x) | ((unsigned)(unsigned short)f2b(v.y) << 16);
        unsigned hi = (unsigned short)f2b(v.z) | ((unsigned)(unsigned short)f2b(v.w) << 16);
        uint2 p; p.x = lo; p.y = hi;
        *(uint2*)&Wl[row][c4] = p;
    }
    // vT half: v[t][64h + e_local] -> vT[e_local][t]
    #pragma unroll
    for (int it = 0; it < 4; ++it) {
        int i = tid + it * 256;               // 1024 float4s
        int t = i >> 4, c4 = (i & 15) * 4;
        float4 vv = *(const float4*)(vc + t * DD + 64 * h + c4);
        vT[c4 + 0][t] = f2b(vv.x); vT[c4 + 1][t] = f2b(vv.y);
        vT[c4 + 2][t] = f2b(vv.z); vT[c4 + 3][t] = f2b(vv.w);
    }
    __syncthreads();

    // phi(k): wave w -> t rows 16w..16w+15, all e
    #pragma unroll
    for (int n = 0; n < 8; ++n) {
        int e = 16 * n + l15;
        f32x4 d = z4;
        #pragma unroll
        for (int kk = 0; kk < 4; ++kk) {
            bf16x8 bw = *(const bf16x8*)&Wl[e][kk * 32 + l4 * 8];
            d = MFMA(afk[kk], bw, d);
        }
        float bv = bias[e];
        #pragma unroll
        for (int j = 0; j < 4; ++j) {
            float zv = d[j] + bv;
            short r = f2b((zv > 0.f) ? (zv + 1.f) : __expf(zv));   // ELU+1
            int t = 16 * w + l4 * 4 + j;
            KfT[e][t] = r;
            if (h == 0) stage[t][e] = r;       // Kf row-major
        }
    }
    // phi(q) (h==1) -> stage row-major
    if (h) {
        #pragma unroll
        for (int n = 0; n < 8; ++n) {
            int e = 16 * n + l15;
            f32x4 d = z4;
            #pragma unroll
            for (int kk = 0; kk < 4; ++kk) {
                bf16x8 bw = *(const bf16x8*)&Wl[e][kk * 32 + l4 * 8];
                d = MFMA(afq[kk], bw, d);
            }
            float bv = bias[e];
            #pragma unroll
            for (int j = 0; j < 4; ++j) {
                float zv = d[j] + bv;
                stage[16 * w + l4 * 4 + j][e] = f2b((zv > 0.f) ? (zv + 1.f) : __expf(zv));
            }
        }
    }
    __syncthreads();

    // stage -> global (h: Qf, else Kf), coalesced
    {
        short* dst = (h ? Qf_g : Kf_g) + (size_t)c * CHK * DD;
        #pragma unroll
        for (int it = 0; it < 4; ++it) {
            int i = tid + it * 256;           // 1024 bf16x8 units
            int t = i >> 4, u = (i & 15) * 8;
            *(bf16x8*)(dst + t * DD + u) = *(const bf16x8*)&stage[t][u];
        }
    }
    // z_c (h==0)
    if (h == 0 && tid < DD) {
        float s = 0.f;
        #pragma unroll
        for (int t8 = 0; t8 < CHK / 8; ++t8) {
            bf16x8 kv = *(const bf16x8*)&KfT[tid][t8 * 8];
            #pragma unroll
            for (int j = 0; j < 8; ++j) s += b2f(kv[j]);
        }
        zc_g[(size_t)c * DD + tid] = s;
    }
    // vT half -> global [c][e][t]
    #pragma unroll
    for (int it = 0; it < 2; ++it) {
        int i = tid + it * 256;               // 512 bf16x8
        int e = i >> 3, t0 = (i & 7) * 8;
        *(bf16x8*)(vT_g + (size_t)c * DD * CHK + (64 * h + e) * CHK + t0) =
            *(const bf16x8*)&vT[e][t0];
    }

    // S-GEMM half: S[d][e_local] = sum_t KfT[d][t] * vT[e_local][t]
    f32x4 sacc[2][4];
    #pragma unroll
    for (int mi = 0; mi < 2; ++mi)
        #pragma unroll
        for (int n = 0; n < 4; ++n) sacc[mi][n] = z4;
    #pragma unroll
    for (int kk = 0; kk < 2; ++kk) {
        bf16x8 afr[2];
        #pragma unroll
        for (int mi = 0; mi < 2; ++mi)
            afr[mi] = *(const bf16x8*)&KfT[16 * (2 * w + mi) + l15][kk * 32 + l4 * 8];
        #pragma unroll
        for (int n = 0; n < 4; ++n) {
            bf16x8 bfr = *(const bf16x8*)&vT[16 * n + l15][kk * 32 + l4 * 8];
            sacc[0][n] = MFMA(afr[0], bfr, sacc[0][n]);
            sacc[1][n] = MFMA(afr[1], bfr, sacc[1][n]);
        }
    }
    __syncthreads();   // stage copy-out done; safe to overwrite

    // sacc -> stage as bf16 Ss[e_local][d]
    #pragma unroll
    for (int mi = 0; mi < 2; ++mi)
        #pragma unroll
        for (int n = 0; n < 4; ++n) {
            int e = 16 * n + l15;
            #pragma unroll
            for (int j = 0; j < 4; ++j)
                stage[e][16 * (2 * w + mi) + l4 * 4 + j] = f2b(sacc[mi][n][j]);
        }
    __syncthreads();

    // stage -> Ss_g bf16 [c][64h+e][d]
    short* dst = Ss_g + (size_t)c * DD * DD + (size_t)(64 * h) * DD;
    #pragma unroll
    for (int it = 0; it < 4; ++it) {
        int i = tid + it * 256;               // 1024 bf16x8
        int e = i >> 4, u = (i & 15) * 8;
        *(bf16x8*)(dst + e * DD + u) = *(const bf16x8*)&stage[e][u];
    }
}

// ---------------------------------------------------------------------------
// K3: block (c, h): fused scan + epilogue.
//     Sp tile = sum of Ss[c' < c] (fp32 regs, L2-served) -> LDS bf16;
//     zp = sum zc[c' < c] -> zs; Qf,Kf -> LDS; QK^T causal -> Ps; den;
//     out half = Ps@V + Q@Sp; divide; store.
// grid 256 x 256. LDS ~62 KB -> 2 blocks/CU. Block order reversed so the
// longest-scan chunks dispatch first.
// ---------------------------------------------------------------------------
__global__ __launch_bounds__(256) void k3_out(const short* __restrict__ Qf_g,
                                              const short* __restrict__ Kf_g,
                                              const short* __restrict__ Ss_g,
                                              const float* __restrict__ zc_g,
                                              const short* __restrict__ vT_g,
                                              float* __restrict__ out) {
    int c = (NCHKS - 1) - (blockIdx.x >> 1);   // reversed: big scans first
    int h = blockIdx.x & 1;
    int cb = c & (NCHK - 1);                   // chunk index within batch
    int b0 = c & ~(NCHK - 1);                  // first chunk of this batch

    __shared__ __align__(16) short Qf[CHK][DD + 8];    // 17408 B
    __shared__ __align__(16) short Kf[CHK][DD + 8];    // 17408 B
    __shared__ __align__(16) short Sp[CHK][DD + 8];    // 17408 B (Sp[e_local][d])
    __shared__ __align__(16) short Ps[CHK][CHK + 8];   // 9216 B
    __shared__ float zs[DD];
    __shared__ float den[CHK];

    int tid = threadIdx.x, lane = tid & 63, w = tid >> 6;
    int l15 = lane & 15, l4 = lane >> 4;
    const f32x4 z4 = {0.f, 0.f, 0.f, 0.f};

    // ---- Qf, Kf global -> LDS (coalesced) ----
    {
        const short* srcq = Qf_g + (size_t)c * CHK * DD;
        const short* srck = Kf_g + (size_t)c * CHK * DD;
        #pragma unroll
        for (int it = 0; it < 4; ++it) {
            int i = tid + it * 256;           // 1024 bf16x8
            int t = i >> 4, u = (i & 15) * 8;
            *(bf16x8*)&Qf[t][u] = *(const bf16x8*)(srcq + t * DD + u);
            *(bf16x8*)&Kf[t][u] = *(const bf16x8*)(srck + t * DD + u);
        }
    }

    // ---- zp scan: zs[d] = sum_{c'<c} zc[c'][d] ----
    if (tid < DD) {
        float s = 0.f;
        for (int c2 = 0; c2 < cb; ++c2)
            s += zc_g[(size_t)(b0 + c2) * DD + tid];
        zs[tid] = s;
    }

    // ---- Sp scan: 32 fp32/thread, statically indexed ----
    {
        float acc0[8] = {0,0,0,0,0,0,0,0}, acc1[8] = {0,0,0,0,0,0,0,0};
        float acc2[8] = {0,0,0,0,0,0,0,0}, acc3[8] = {0,0,0,0,0,0,0,0};
        int e0 = tid >> 4, u0 = (tid & 15) * 8;               // it=0: i=tid
        int e1 = (tid + 256) >> 4, u1 = u0;                   // it=1
        int e2 = (tid + 512) >> 4, u2 = u0;                   // it=2
        int e3 = (tid + 768) >> 4, u3 = u0;                   // it=3
        const short* base = Ss_g + (size_t)64 * h * DD;
        for (int c2 = 0; c2 < cb; ++c2) {
            const short* src = base + (size_t)(b0 + c2) * DD * DD;
            bf16x8 v0 = *(const bf16x8*)(src + e0 * DD + u0);
            bf16x8 v1 = *(const bf16x8*)(src + e1 * DD + u1);
            bf16x8 v2 = *(const bf16x8*)(src + e2 * DD + u2);
            bf16x8 v3 = *(const bf16x8*)(src + e3 * DD + u3);
            #pragma unroll
            for (int j = 0; j < 8; ++j) {
                acc0[j] += b2f(v0[j]); acc1[j] += b2f(v1[j]);
                acc2[j] += b2f(v2[j]); acc3[j] += b2f(v3[j]);
            }
        }
        #pragma unroll
        for (int j = 0; j < 8; ++j) {
            Sp[e0][u0 + j] = f2b(acc0[j]); Sp[e1][u1 + j] = f2b(acc1[j]);
            Sp[e2][u2 + j] = f2b(acc2[j]); Sp[e3][u3 + j] = f2b(acc3[j]);
        }
    }
    __syncthreads();

    // ---- QK^T causal -> Ps ----
    bf16x8 aq[4];
    #pragma unroll
    for (int kk = 0; kk < 4; ++kk)
        aq[kk] = *(const bf16x8*)&Qf[16 * w + l15][kk * 32 + l4 * 8];
    #pragma unroll
    for (int n2 = 0; n2 < 4; ++n2) {
        f32x4 p = z4;
        #pragma unroll
        for (int kk = 0; kk < 4; ++kk) {
            bf16x8 bk = *(const bf16x8*)&Kf[16 * n2 + l15][kk * 32 + l4 * 8];
            p = MFMA(aq[kk], bk, p);
        }
        int t2 = 16 * n2 + l15;
        #pragma unroll
        for (int j = 0; j < 4; ++j) {
            int t = 16 * w + l4 * 4 + j;
            Ps[t][t2] = (t2 <= t) ? f2b(p[j]) : (short)0;
        }
    }
    __syncthreads();

    // ---- den (wave 0) ----
    if (tid < CHK) {
        float s = 1e-6f;
        #pragma unroll
        for (int t8 = 0; t8 < CHK / 8; ++t8) {
            bf16x8 pv = *(const bf16x8*)&Ps[tid][t8 * 8];
            #pragma unroll
            for (int j = 0; j < 8; ++j) s += b2f(pv[j]);
        }
        #pragma unroll
        for (int d8 = 0; d8 < DD / 8; ++d8) {
            bf16x8 qv = *(const bf16x8*)&Qf[tid][d8 * 8];
            #pragma unroll
            for (int j = 0; j < 8; ++j) s += b2f(qv[j]) * zs[d8 * 8 + j];
        }
        den[tid] = s;
    }

    // ---- out half: e = 64h + 16n + l15, n = 0..3 ----
    bf16x8 ap[2];
    #pragma unroll
    for (int kk = 0; kk < 2; ++kk)
        ap[kk] = *(const bf16x8*)&Ps[16 * w + l15][kk * 32 + l4 * 8];

    const short* vTg = vT_g + (size_t)c * DD * CHK;
    f32x4 oacc[4];
    #pragma unroll
    for (int n = 0; n < 4; ++n) oacc[n] = z4;
    #pragma unroll
    for (int n = 0; n < 4; ++n) {
        int el = 16 * n + l15;                // e_local in Sp tile
        int e  = 64 * h + el;
        #pragma unroll
        for (int kk = 0; kk < 4; ++kk) {
            bf16x8 bs = *(const bf16x8*)&Sp[el][kk * 32 + l4 * 8];
            oacc[n] = MFMA(aq[kk], bs, oacc[n]);
        }
        #pragma unroll
        for (int kk = 0; kk < 2; ++kk) {
            bf16x8 bv = *(const bf16x8*)(vTg + e * CHK + kk * 32 + l4 * 8);
            oacc[n] = MFMA(ap[kk], bv, oacc[n]);
        }
    }
    __syncthreads();   // den ready

    float* oc = out + (size_t)c * CHK * DD;
    float invs[4];
    #pragma unroll
    for (int j = 0; j < 4; ++j) invs[j] = 1.0f / den[16 * w + l4 * 4 + j];
    #pragma unroll
    for (int n = 0; n < 4; ++n) {
        int e = 64 * h + 16 * n + l15;
        #pragma unroll
        for (int j = 0; j < 4; ++j) {
            int t = 16 * w + l4 * 4 + j;
            oc[t * DD + e] = oacc[n][j] * invs[j];
        }
    }
}

// ---------------------------------------------------------------------------
extern "C" void kernel_launch(void* const* d_in, const int* in_sizes, int n_in,
                              void* d_out, int out_size, void* d_ws, size_t ws_size,
                              hipStream_t stream) {
    const float* q  = (const float*)d_in[0];
    const float* k  = (const float*)d_in[1];
    const float* v  = (const float*)d_in[2];
    const float* W  = (const float*)d_in[3];
    const float* bi = (const float*)d_in[4];
    float* out = (float*)d_out;

    float* zc_g = (float*)d_ws;                         // 16384 f32
    short* Ss_g = (short*)(zc_g + (size_t)NCHKS * DD);  // 4 MB
    short* vT_g = Ss_g + (size_t)NCHKS * DD * DD;       // 2 MB
    short* Qf_g = vT_g + (size_t)NCHKS * DD * CHK;      // 2 MB
    short* Kf_g = Qf_g + (size_t)NCHKS * CHK * DD;      // 2 MB

    k1_chunk<<<2 * NCHKS, 256, 0, stream>>>(q, k, v, W, bi, Ss_g, zc_g, vT_g, Qf_g, Kf_g);
    k3_out<<<2 * NCHKS, 256, 0, stream>>>(Qf_g, Kf_g, Ss_g, zc_g, vT_g, out);
}

// Round 9
// 31.710 us; speedup vs baseline: 1.2805x; 1.2805x over previous
//
#include <hip/hip_runtime.h>
#include <hip/hip_bf16.h>

#define BB 4
#define TT 2048
#define DD 128
#define CHK 64
#define NCHK 32            // TT/CHK
#define NCHKS (BB*NCHK)    // 128 chunks total

typedef __attribute__((ext_vector_type(8))) short  bf16x8;
typedef __attribute__((ext_vector_type(4))) float  f32x4;

#define MFMA(a,b,c) __builtin_amdgcn_mfma_f32_16x16x32_bf16(a, b, c, 0, 0, 0)

__device__ __forceinline__ short f2b(float f) {
    union { float f; unsigned u; } x; x.f = f;
    unsigned r = x.u + 0x7fffu + ((x.u >> 16) & 1u);   // RNE
    return (short)(r >> 16);
}
__device__ __forceinline__ float b2f(short s) {
    union { unsigned u; float f; } x; x.u = ((unsigned)(unsigned short)s) << 16;
    return x.f;
}
__device__ __forceinline__ bf16x8 cvt8(const float* p) {
    float4 a = *(const float4*)p, b = *(const float4*)(p + 4);
    bf16x8 r;
    r[0]=f2b(a.x); r[1]=f2b(a.y); r[2]=f2b(a.z); r[3]=f2b(a.w);
    r[4]=f2b(b.x); r[5]=f2b(b.y); r[6]=f2b(b.z); r[7]=f2b(b.w);
    return r;
}

// ---------------------------------------------------------------------------
// K1: block (c, h2): e-quarter split for 2 blocks/CU (2 waves/SIMD).
//     phi(k) full -> KfT; h2==0: stage Kf -> global; h2==1: phi(q) -> Qf_g;
//     h2==2: z_c. vT quarter -> global; S_quarter = Kf^T V_q -> Ss_g bf16.
// grid 512 x 256. LDS ~75.3 KB -> 2 blocks/CU.
// ---------------------------------------------------------------------------
__global__ __launch_bounds__(256, 2) void k1_chunk(const float* __restrict__ q,
                                                   const float* __restrict__ kin,
                                                   const float* __restrict__ vin,
                                                   const float* __restrict__ W,
                                                   const float* __restrict__ bias,
                                                   short* __restrict__ Ss_g,
                                                   float* __restrict__ zc_g,
                                                   short* __restrict__ vT_g,
                                                   short* __restrict__ Qf_g,
                                                   short* __restrict__ Kf_g) {
    int c = blockIdx.x >> 2, h2 = blockIdx.x & 3;
    int eq0 = 32 * h2;
    const float* qc = q   + (size_t)c * CHK * DD;
    const float* kc = kin + (size_t)c * CHK * DD;
    const float* vc = vin + (size_t)c * CHK * DD;

    __shared__ __align__(16) short Wl  [DD][DD + 8];    // 34816 B
    __shared__ __align__(16) short KfT [DD][CHK + 8];   // 18432 B  (KfT[d][t])
    __shared__ __align__(16) short vT  [32][CHK + 8];   // 4608 B   (vT[e_local][t])
    __shared__ __align__(16) short stage[CHK][DD + 8];  // 17408 B  Qf/Kf rowmajor, then Ss bf16

    int tid = threadIdx.x, lane = tid & 63, w = tid >> 6;
    int l15 = lane & 15, l4 = lane >> 4;
    const f32x4 z4 = {0.f, 0.f, 0.f, 0.f};

    // prefetch A-fragments (k always; q on h2==1)
    bf16x8 afk[4], afq[4];
    {
        int row = 16 * w + l15;
        #pragma unroll
        for (int kk = 0; kk < 4; ++kk) afk[kk] = cvt8(kc + row * DD + kk * 32 + l4 * 8);
        if (h2 == 1) {
            #pragma unroll
            for (int kk = 0; kk < 4; ++kk) afq[kk] = cvt8(qc + row * DD + kk * 32 + l4 * 8);
        }
    }
    // W fp32 -> LDS bf16 (padded rows)
    #pragma unroll
    for (int it = 0; it < 16; ++it) {
        int i = tid + it * 256;               // 4096 float4s
        int row = i >> 5, c4 = (i & 31) * 4;
        float4 v = *(const float4*)(W + (size_t)row * DD + c4);
        unsigned lo = (unsigned short)f2b(v.x) | ((unsigned)(unsigned short)f2b(v.y) << 16);
        unsigned hi = (unsigned short)f2b(v.z) | ((unsigned)(unsigned short)f2b(v.w) << 16);
        uint2 p; p.x = lo; p.y = hi;
        *(uint2*)&Wl[row][c4] = p;
    }
    // vT quarter: v[t][eq0 + el], el 0..31 -> vT[el][t]; 512 float4s
    #pragma unroll
    for (int it = 0; it < 2; ++it) {
        int i = tid + it * 256;               // 0..511
        int t = i >> 3, c4 = (i & 7) * 4;
        float4 vv = *(const float4*)(vc + t * DD + eq0 + c4);
        vT[c4 + 0][t] = f2b(vv.x); vT[c4 + 1][t] = f2b(vv.y);
        vT[c4 + 2][t] = f2b(vv.z); vT[c4 + 3][t] = f2b(vv.w);
    }
    __syncthreads();

    // phi(k): wave w -> t rows 16w..16w+15, all e
    #pragma unroll
    for (int n = 0; n < 8; ++n) {
        int e = 16 * n + l15;
        f32x4 d = z4;
        #pragma unroll
        for (int kk = 0; kk < 4; ++kk) {
            bf16x8 bw = *(const bf16x8*)&Wl[e][kk * 32 + l4 * 8];
            d = MFMA(afk[kk], bw, d);
        }
        float bv = bias[e];
        #pragma unroll
        for (int j = 0; j < 4; ++j) {
            float zv = d[j] + bv;
            short r = f2b((zv > 0.f) ? (zv + 1.f) : __expf(zv));   // ELU+1
            int t = 16 * w + l4 * 4 + j;
            KfT[e][t] = r;
            if (h2 == 0) stage[t][e] = r;      // Kf row-major
        }
    }
    // phi(q) (h2==1) -> stage row-major
    if (h2 == 1) {
        #pragma unroll
        for (int n = 0; n < 8; ++n) {
            int e = 16 * n + l15;
            f32x4 d = z4;
            #pragma unroll
            for (int kk = 0; kk < 4; ++kk) {
                bf16x8 bw = *(const bf16x8*)&Wl[e][kk * 32 + l4 * 8];
                d = MFMA(afq[kk], bw, d);
            }
            float bv = bias[e];
            #pragma unroll
            for (int j = 0; j < 4; ++j) {
                float zv = d[j] + bv;
                stage[16 * w + l4 * 4 + j][e] = f2b((zv > 0.f) ? (zv + 1.f) : __expf(zv));
            }
        }
    }
    __syncthreads();

    // stage -> global (h2==0: Kf, h2==1: Qf), coalesced
    if (h2 < 2) {
        short* dst = (h2 ? Qf_g : Kf_g) + (size_t)c * CHK * DD;
        #pragma unroll
        for (int it = 0; it < 4; ++it) {
            int i = tid + it * 256;           // 1024 bf16x8 units
            int t = i >> 4, u = (i & 15) * 8;
            *(bf16x8*)(dst + t * DD + u) = *(const bf16x8*)&stage[t][u];
        }
    }
    // z_c (h2==2)
    if (h2 == 2 && tid < DD) {
        float s = 0.f;
        #pragma unroll
        for (int t8 = 0; t8 < CHK / 8; ++t8) {
            bf16x8 kv = *(const bf16x8*)&KfT[tid][t8 * 8];
            #pragma unroll
            for (int j = 0; j < 8; ++j) s += b2f(kv[j]);
        }
        zc_g[(size_t)c * DD + tid] = s;
    }
    // vT quarter -> global [c][eq0+el][t]; 256 bf16x8 units
    if (tid < 256) {
        int e = tid >> 3, t0 = (tid & 7) * 8;
        *(bf16x8*)(vT_g + (size_t)c * DD * CHK + (eq0 + e) * CHK + t0) =
            *(const bf16x8*)&vT[e][t0];
    }

    // S-GEMM quarter: S[d][el] = sum_t KfT[d][t] * vT[el][t], el = 16n+l15, n<2
    f32x4 sacc[2][2];
    #pragma unroll
    for (int mi = 0; mi < 2; ++mi)
        #pragma unroll
        for (int n = 0; n < 2; ++n) sacc[mi][n] = z4;
    #pragma unroll
    for (int kk = 0; kk < 2; ++kk) {
        bf16x8 afr[2];
        #pragma unroll
        for (int mi = 0; mi < 2; ++mi)
            afr[mi] = *(const bf16x8*)&KfT[16 * (2 * w + mi) + l15][kk * 32 + l4 * 8];
        #pragma unroll
        for (int n = 0; n < 2; ++n) {
            bf16x8 bfr = *(const bf16x8*)&vT[16 * n + l15][kk * 32 + l4 * 8];
            sacc[0][n] = MFMA(afr[0], bfr, sacc[0][n]);
            sacc[1][n] = MFMA(afr[1], bfr, sacc[1][n]);
        }
    }
    __syncthreads();   // stage copy-out done; safe to overwrite

    // sacc -> stage as bf16 Ss[el][d], el 0..31
    #pragma unroll
    for (int mi = 0; mi < 2; ++mi)
        #pragma unroll
        for (int n = 0; n < 2; ++n) {
            int el = 16 * n + l15;
            #pragma unroll
            for (int j = 0; j < 4; ++j)
                stage[el][16 * (2 * w + mi) + l4 * 4 + j] = f2b(sacc[mi][n][j]);
        }
    __syncthreads();

    // stage -> Ss_g bf16 [c][eq0+el][d]; 512 bf16x8 units
    short* dst = Ss_g + (size_t)c * DD * DD + (size_t)eq0 * DD;
    #pragma unroll
    for (int it = 0; it < 2; ++it) {
        int i = tid + it * 256;               // 0..511
        int el = i >> 4, u = (i & 15) * 8;
        *(bf16x8*)(dst + el * DD + u) = *(const bf16x8*)&stage[el][u];
    }
}

// ---------------------------------------------------------------------------
// K2: exclusive prefix over chunks (bf16 in/out, fp32 accum).
// grid 512 = (b,e) x 128 thr (thread = d).
// ---------------------------------------------------------------------------
__global__ __launch_bounds__(128) void k2_scan(const short* __restrict__ Ss_g,
                                               const float* __restrict__ zc_g,
                                               short* __restrict__ Sp_g,
                                               float* __restrict__ zp_g) {
    int e = blockIdx.x & 127, b = blockIdx.x >> 7;
    int d = threadIdx.x;
    size_t base = ((size_t)(b * NCHK) * DD + e) * DD + d;
    const size_t stride = (size_t)DD * DD;

    float vals[NCHK];
    #pragma unroll
    for (int c2 = 0; c2 < NCHK; ++c2) vals[c2] = b2f(Ss_g[base + c2 * stride]);
    float run = 0.f;
    #pragma unroll
    for (int c2 = 0; c2 < NCHK; ++c2) {
        Sp_g[base + c2 * stride] = f2b(run);
        run += vals[c2];
    }
    if (e == 0) {
        float vz[NCHK];
        #pragma unroll
        for (int c2 = 0; c2 < NCHK; ++c2) vz[c2] = zc_g[(size_t)(b * NCHK + c2) * DD + d];
        float rz = 0.f;
        #pragma unroll
        for (int c2 = 0; c2 < NCHK; ++c2) {
            zp_g[(size_t)(b * NCHK + c2) * DD + d] = rz;
            rz += vz[c2];
        }
    }
}

// ---------------------------------------------------------------------------
// K3: block (c, h2): e-quarter epilogue. Qf, Kf coalesced global -> LDS.
//     P=QK^T causal -> Ps bf16; den (wave0); out quarter = Ps@V + Q@Sp.
// grid 512 x 256. LDS ~44.8 KB -> 2 blocks/CU.
// ---------------------------------------------------------------------------
__global__ __launch_bounds__(256, 2) void k3_out(const short* __restrict__ Qf_g,
                                                 const short* __restrict__ Kf_g,
                                                 const short* __restrict__ Sp_g,
                                                 const float* __restrict__ zp_g,
                                                 const short* __restrict__ vT_g,
                                                 float* __restrict__ out) {
    int c = blockIdx.x >> 2, h2 = blockIdx.x & 3;

    __shared__ __align__(16) short Qf[CHK][DD + 8];    // 17408 B
    __shared__ __align__(16) short Kf[CHK][DD + 8];    // 17408 B
    __shared__ __align__(16) short Ps[CHK][CHK + 8];   // 9216 B
    __shared__ float zs[DD];
    __shared__ float den[CHK];

    int tid = threadIdx.x, lane = tid & 63, w = tid >> 6;
    int l15 = lane & 15, l4 = lane >> 4;
    const f32x4 z4 = {0.f, 0.f, 0.f, 0.f};

    if (tid < DD) zs[tid] = zp_g[(size_t)c * DD + tid];

    // Qf, Kf global -> LDS (coalesced)
    {
        const short* srcq = Qf_g + (size_t)c * CHK * DD;
        const short* srck = Kf_g + (size_t)c * CHK * DD;
        #pragma unroll
        for (int it = 0; it < 4; ++it) {
            int i = tid + it * 256;           // 1024 bf16x8
            int t = i >> 4, u = (i & 15) * 8;
            *(bf16x8*)&Qf[t][u] = *(const bf16x8*)(srcq + t * DD + u);
            *(bf16x8*)&Kf[t][u] = *(const bf16x8*)(srck + t * DD + u);
        }
    }
    __syncthreads();

    // QK^T causal -> Ps
    bf16x8 aq[4];
    #pragma unroll
    for (int kk = 0; kk < 4; ++kk)
        aq[kk] = *(const bf16x8*)&Qf[16 * w + l15][kk * 32 + l4 * 8];
    #pragma unroll
    for (int n2 = 0; n2 < 4; ++n2) {
        f32x4 p = z4;
        #pragma unroll
        for (int kk = 0; kk < 4; ++kk) {
            bf16x8 bk = *(const bf16x8*)&Kf[16 * n2 + l15][kk * 32 + l4 * 8];
            p = MFMA(aq[kk], bk, p);
        }
        int t2 = 16 * n2 + l15;
        #pragma unroll
        for (int j = 0; j < 4; ++j) {
            int t = 16 * w + l4 * 4 + j;
            Ps[t][t2] = (t2 <= t) ? f2b(p[j]) : (short)0;
        }
    }
    __syncthreads();

    // den (wave 0; waves 1-3 proceed to out MFMAs)
    if (tid < CHK) {
        float s = 1e-6f;
        #pragma unroll
        for (int t8 = 0; t8 < CHK / 8; ++t8) {
            bf16x8 pv = *(const bf16x8*)&Ps[tid][t8 * 8];
            #pragma unroll
            for (int j = 0; j < 8; ++j) s += b2f(pv[j]);
        }
        #pragma unroll
        for (int d8 = 0; d8 < DD / 8; ++d8) {
            bf16x8 qv = *(const bf16x8*)&Qf[tid][d8 * 8];
            #pragma unroll
            for (int j = 0; j < 8; ++j) s += b2f(qv[j]) * zs[d8 * 8 + j];
        }
        den[tid] = s;
    }

    // out quarter: e = 32*h2 + 16n + l15, n = 0..1
    bf16x8 ap[2];
    #pragma unroll
    for (int kk = 0; kk < 2; ++kk)
        ap[kk] = *(const bf16x8*)&Ps[16 * w + l15][kk * 32 + l4 * 8];

    const short* Sp  = Sp_g + (size_t)c * DD * DD;
    const short* vTg = vT_g + (size_t)c * DD * CHK;
    f32x4 oacc[2];
    oacc[0] = z4; oacc[1] = z4;
    #pragma unroll
    for (int n = 0; n < 2; ++n) {
        int e = 32 * h2 + 16 * n + l15;
        #pragma unroll
        for (int kk = 0; kk < 4; ++kk) {
            bf16x8 bs = *(const bf16x8*)(Sp + e * DD + kk * 32 + l4 * 8);
            oacc[n] = MFMA(aq[kk], bs, oacc[n]);
        }
        #pragma unroll
        for (int kk = 0; kk < 2; ++kk) {
            bf16x8 bv = *(const bf16x8*)(vTg + e * CHK + kk * 32 + l4 * 8);
            oacc[n] = MFMA(ap[kk], bv, oacc[n]);
        }
    }
    __syncthreads();   // den ready

    float* oc = out + (size_t)c * CHK * DD;
    float invs[4];
    #pragma unroll
    for (int j = 0; j < 4; ++j) invs[j] = 1.0f / den[16 * w + l4 * 4 + j];
    #pragma unroll
    for (int n = 0; n < 2; ++n) {
        int e = 32 * h2 + 16 * n + l15;
        #pragma unroll
        for (int j = 0; j < 4; ++j) {
            int t = 16 * w + l4 * 4 + j;
            oc[t * DD + e] = oacc[n][j] * invs[j];
        }
    }
}

// ---------------------------------------------------------------------------
extern "C" void kernel_launch(void* const* d_in, const int* in_sizes, int n_in,
                              void* d_out, int out_size, void* d_ws, size_t ws_size,
                              hipStream_t stream) {
    const float* q  = (const float*)d_in[0];
    const float* k  = (const float*)d_in[1];
    const float* v  = (const float*)d_in[2];
    const float* W  = (const float*)d_in[3];
    const float* bi = (const float*)d_in[4];
    float* out = (float*)d_out;

    float* zc_g = (float*)d_ws;                         // 16384 f32
    float* zp_g = zc_g + (size_t)NCHKS * DD;            // 16384 f32
    short* Ss_g = (short*)(zp_g + (size_t)NCHKS * DD);  // 4 MB
    short* Sp_g = Ss_g + (size_t)NCHKS * DD * DD;       // 4 MB
    short* vT_g = Sp_g + (size_t)NCHKS * DD * DD;       // 2 MB
    short* Qf_g = vT_g + (size_t)NCHKS * DD * CHK;      // 2 MB
    short* Kf_g = Qf_g + (size_t)NCHKS * CHK * DD;      // 2 MB

    k1_chunk<<<4 * NCHKS, 256, 0, stream>>>(q, k, v, W, bi, Ss_g, zc_g, vT_g, Qf_g, Kf_g);
    k2_scan<<<512, 128, 0, stream>>>(Ss_g, zc_g, Sp_g, zp_g);
    k3_out<<<4 * NCHKS, 256, 0, stream>>>(Qf_g, Kf_g, Sp_g, zp_g, vT_g, out);
}

// Round 10
// 27.053 us; speedup vs baseline: 1.5009x; 1.1722x over previous
//
#include <hip/hip_runtime.h>
#include <hip/hip_bf16.h>

#define BB 4
#define TT 2048
#define DD 128
#define CHK 64
#define NCHK 32            // TT/CHK
#define NCHKS (BB*NCHK)    // 128 chunks total

typedef __attribute__((ext_vector_type(8))) short  bf16x8;
typedef __attribute__((ext_vector_type(4))) float  f32x4;

#define MFMA(a,b,c) __builtin_amdgcn_mfma_f32_16x16x32_bf16(a, b, c, 0, 0, 0)

__device__ __forceinline__ short f2b(float f) {
    union { float f; unsigned u; } x; x.f = f;
    unsigned r = x.u + 0x7fffu + ((x.u >> 16) & 1u);   // RNE
    return (short)(r >> 16);
}
__device__ __forceinline__ float b2f(short s) {
    union { unsigned u; float f; } x; x.u = ((unsigned)(unsigned short)s) << 16;
    return x.f;
}
__device__ __forceinline__ bf16x8 cvt8(const float* p) {
    float4 a = *(const float4*)p, b = *(const float4*)(p + 4);
    bf16x8 r;
    r[0]=f2b(a.x); r[1]=f2b(a.y); r[2]=f2b(a.z); r[3]=f2b(a.w);
    r[4]=f2b(b.x); r[5]=f2b(b.y); r[6]=f2b(b.z); r[7]=f2b(b.w);
    return r;
}

// ---------------------------------------------------------------------------
// K1: block (c, dh): d-half split. Computes phi(q) AND phi(k) for d in
//     [64dh, 64dh+64) only (half of W staged, 16+16 MFMAs), z_c half,
//     Qf/Kf d-half staged to global, S[d-half][e-full] -> Ss_g bf16 [c][e][d].
//     dh==0 additionally stores vT.
// grid 256 x 256. LDS ~62 KB -> 2 blocks/CU.
// ---------------------------------------------------------------------------
__global__ __launch_bounds__(256, 2) void k1_chunk(const float* __restrict__ q,
                                                   const float* __restrict__ kin,
                                                   const float* __restrict__ vin,
                                                   const float* __restrict__ W,
                                                   const float* __restrict__ bias,
                                                   short* __restrict__ Ss_g,
                                                   float* __restrict__ zc_g,
                                                   short* __restrict__ vT_g,
                                                   short* __restrict__ Qf_g,
                                                   short* __restrict__ Kf_g) {
    int c = blockIdx.x >> 1, dh = blockIdx.x & 1;
    int d0 = 64 * dh;
    const float* qc = q   + (size_t)c * CHK * DD;
    const float* kc = kin + (size_t)c * CHK * DD;
    const float* vc = vin + (size_t)c * CHK * DD;

    __shared__ __align__(16) short Wl [64][DD + 8];     // 17408 B  W rows d0..d0+63
    __shared__ __align__(16) short KfT[64][CHK + 8];    // 9216 B   (KfT[dl][t])
    __shared__ __align__(16) short vT [DD][CHK + 8];    // 18432 B  (vT[e][t])
    __shared__ __align__(16) short stage[2][CHK][CHK + 8]; // 18432 B: [0]=Kf [t][dl], [1]=Qf; later Ss [e][dl]

    int tid = threadIdx.x, lane = tid & 63, w = tid >> 6;
    int l15 = lane & 15, l4 = lane >> 4;
    const f32x4 z4 = {0.f, 0.f, 0.f, 0.f};

    // prefetch A-fragments for both q and k (rows t = 16w + l15, full D)
    bf16x8 afk[4], afq[4];
    {
        int row = 16 * w + l15;
        #pragma unroll
        for (int kk = 0; kk < 4; ++kk) {
            afk[kk] = cvt8(kc + row * DD + kk * 32 + l4 * 8);
            afq[kk] = cvt8(qc + row * DD + kk * 32 + l4 * 8);
        }
    }
    // W d-half fp32 -> LDS bf16 (2048 float4s)
    #pragma unroll
    for (int it = 0; it < 8; ++it) {
        int i = tid + it * 256;
        int row = i >> 5, c4 = (i & 31) * 4;
        float4 v = *(const float4*)(W + (size_t)(d0 + row) * DD + c4);
        unsigned lo = (unsigned short)f2b(v.x) | ((unsigned)(unsigned short)f2b(v.y) << 16);
        unsigned hi = (unsigned short)f2b(v.z) | ((unsigned)(unsigned short)f2b(v.w) << 16);
        uint2 p; p.x = lo; p.y = hi;
        *(uint2*)&Wl[row][c4] = p;
    }
    // vT full: v[t][e] -> vT[e][t]  (2048 float4s)
    #pragma unroll
    for (int it = 0; it < 8; ++it) {
        int i = tid + it * 256;
        int t = i >> 5, e4 = (i & 31) * 4;
        float4 vv = *(const float4*)(vc + t * DD + e4);
        vT[e4 + 0][t] = f2b(vv.x); vT[e4 + 1][t] = f2b(vv.y);
        vT[e4 + 2][t] = f2b(vv.z); vT[e4 + 3][t] = f2b(vv.w);
    }
    __syncthreads();

    // phi(k), phi(q) for d-half: wave w -> t rows 16w..16w+15, dl = 16n+l15
    #pragma unroll
    for (int n = 0; n < 4; ++n) {
        int dl = 16 * n + l15;
        f32x4 dk = z4, dq = z4;
        #pragma unroll
        for (int kk = 0; kk < 4; ++kk) {
            bf16x8 bw = *(const bf16x8*)&Wl[dl][kk * 32 + l4 * 8];
            dk = MFMA(afk[kk], bw, dk);
            dq = MFMA(afq[kk], bw, dq);
        }
        float bv = bias[d0 + dl];
        #pragma unroll
        for (int j = 0; j < 4; ++j) {
            int t = 16 * w + l4 * 4 + j;
            float zk = dk[j] + bv;
            short rk = f2b((zk > 0.f) ? (zk + 1.f) : __expf(zk));   // ELU+1
            KfT[dl][t] = rk;
            stage[0][t][dl] = rk;
            float zq = dq[j] + bv;
            stage[1][t][dl] = f2b((zq > 0.f) ? (zq + 1.f) : __expf(zq));
        }
    }
    __syncthreads();

    // Kf_g / Qf_g d-half stores: 64t x 64dl = 512 bf16x8 units each
    {
        short* dk_ = Kf_g + (size_t)c * CHK * DD + d0;
        short* dq_ = Qf_g + (size_t)c * CHK * DD + d0;
        #pragma unroll
        for (int it = 0; it < 2; ++it) {
            int i = tid + it * 256;
            int t = i >> 3, u = (i & 7) * 8;
            *(bf16x8*)(dk_ + t * DD + u) = *(const bf16x8*)&stage[0][t][u];
            *(bf16x8*)(dq_ + t * DD + u) = *(const bf16x8*)&stage[1][t][u];
        }
    }
    // z_c d-half
    if (tid < 64) {
        float s = 0.f;
        #pragma unroll
        for (int t8 = 0; t8 < CHK / 8; ++t8) {
            bf16x8 kv = *(const bf16x8*)&KfT[tid][t8 * 8];
            #pragma unroll
            for (int j = 0; j < 8; ++j) s += b2f(kv[j]);
        }
        zc_g[(size_t)c * DD + d0 + tid] = s;
    }
    // vT -> global (dh==0 only): 1024 bf16x8 units
    if (dh == 0) {
        #pragma unroll
        for (int it = 0; it < 4; ++it) {
            int i = tid + it * 256;
            int e = i >> 3, t0 = (i & 7) * 8;
            *(bf16x8*)(vT_g + (size_t)c * DD * CHK + e * CHK + t0) =
                *(const bf16x8*)&vT[e][t0];
        }
    }

    // S-GEMM: S[dl][e] = sum_t KfT[dl][t] * vT[e][t]; wave w -> dl tile [16w,16w+16)
    f32x4 sacc[8];
    #pragma unroll
    for (int n = 0; n < 8; ++n) sacc[n] = z4;
    #pragma unroll
    for (int kk = 0; kk < 2; ++kk) {
        bf16x8 afr = *(const bf16x8*)&KfT[16 * w + l15][kk * 32 + l4 * 8];
        #pragma unroll
        for (int n = 0; n < 8; ++n) {
            bf16x8 bfr = *(const bf16x8*)&vT[16 * n + l15][kk * 32 + l4 * 8];
            sacc[n] = MFMA(afr, bfr, sacc[n]);
        }
    }
    __syncthreads();   // stage copy-out done; safe to overwrite

    // sacc -> stage reinterpreted as Ss[e][dl] bf16 ([128][72])
    short (*st)[CHK + 8] = (short(*)[CHK + 8])&stage[0][0][0];
    #pragma unroll
    for (int n = 0; n < 8; ++n) {
        int e = 16 * n + l15;
        #pragma unroll
        for (int j = 0; j < 4; ++j)
            st[e][16 * w + l4 * 4 + j] = f2b(sacc[n][j]);
    }
    __syncthreads();

    // Ss store: [c][e][d0 + dl], 1024 bf16x8 units
    short* dst = Ss_g + (size_t)c * DD * DD + d0;
    #pragma unroll
    for (int it = 0; it < 4; ++it) {
        int i = tid + it * 256;
        int e = i >> 3, u = (i & 7) * 8;
        *(bf16x8*)(dst + e * DD + u) = *(const bf16x8*)&st[e][u];
    }
}

// ---------------------------------------------------------------------------
// K2: exclusive prefix over chunks (bf16 in/out, fp32 accum).
// grid 512 = (b,e) x 128 thr (thread = d).
// ---------------------------------------------------------------------------
__global__ __launch_bounds__(128) void k2_scan(const short* __restrict__ Ss_g,
                                               const float* __restrict__ zc_g,
                                               short* __restrict__ Sp_g,
                                               float* __restrict__ zp_g) {
    int e = blockIdx.x & 127, b = blockIdx.x >> 7;
    int d = threadIdx.x;
    size_t base = ((size_t)(b * NCHK) * DD + e) * DD + d;
    const size_t stride = (size_t)DD * DD;

    float vals[NCHK];
    #pragma unroll
    for (int c2 = 0; c2 < NCHK; ++c2) vals[c2] = b2f(Ss_g[base + c2 * stride]);
    float run = 0.f;
    #pragma unroll
    for (int c2 = 0; c2 < NCHK; ++c2) {
        Sp_g[base + c2 * stride] = f2b(run);
        run += vals[c2];
    }
    if (e == 0) {
        float vz[NCHK];
        #pragma unroll
        for (int c2 = 0; c2 < NCHK; ++c2) vz[c2] = zc_g[(size_t)(b * NCHK + c2) * DD + d];
        float rz = 0.f;
        #pragma unroll
        for (int c2 = 0; c2 < NCHK; ++c2) {
            zp_g[(size_t)(b * NCHK + c2) * DD + d] = rz;
            rz += vz[c2];
        }
    }
}

// ---------------------------------------------------------------------------
// K3: block (c, h): epilogue. Qf, Kf coalesced global -> LDS.
//     QK^T causal -> Ps bf16 with in-register masked rowsum; den via virtual
//     zp-column MFMA + shfl_xor reduce (no serial loop, single barrier).
//     out half = Ps@V + Q@Sp; divide; store.
// grid 256 x 256. LDS ~44.3 KB.
// ---------------------------------------------------------------------------
__global__ __launch_bounds__(256) void k3_out(const short* __restrict__ Qf_g,
                                              const short* __restrict__ Kf_g,
                                              const short* __restrict__ Sp_g,
                                              const float* __restrict__ zp_g,
                                              const short* __restrict__ vT_g,
                                              float* __restrict__ out) {
    int c = blockIdx.x >> 1, h = blockIdx.x & 1;

    __shared__ __align__(16) short Qf[CHK][DD + 8];    // 17408 B
    __shared__ __align__(16) short Kf[CHK][DD + 8];    // 17408 B
    __shared__ __align__(16) short Ps[CHK][CHK + 8];   // 9216 B
    __shared__ float den[CHK];

    int tid = threadIdx.x, lane = tid & 63, w = tid >> 6;
    int l15 = lane & 15, l4 = lane >> 4;
    const f32x4 z4 = {0.f, 0.f, 0.f, 0.f};

    // virtual zp column B-frags (fragment row l15==0 carries zp, else 0)
    const float* zp = zp_g + (size_t)c * DD;
    bf16x8 bz[4];
    #pragma unroll
    for (int kk = 0; kk < 4; ++kk) {
        bf16x8 zf = cvt8(zp + kk * 32 + l4 * 8);
        bf16x8 zero = {0,0,0,0,0,0,0,0};
        bz[kk] = (l15 == 0) ? zf : zero;
    }

    // Qf, Kf global -> LDS (coalesced)
    {
        const short* srcq = Qf_g + (size_t)c * CHK * DD;
        const short* srck = Kf_g + (size_t)c * CHK * DD;
        #pragma unroll
        for (int it = 0; it < 4; ++it) {
            int i = tid + it * 256;           // 1024 bf16x8
            int t = i >> 4, u = (i & 15) * 8;
            *(bf16x8*)&Qf[t][u] = *(const bf16x8*)(srcq + t * DD + u);
            *(bf16x8*)&Kf[t][u] = *(const bf16x8*)(srck + t * DD + u);
        }
    }
    __syncthreads();

    // Q A-frags (rows t = 16w + l15)
    bf16x8 aq[4];
    #pragma unroll
    for (int kk = 0; kk < 4; ++kk)
        aq[kk] = *(const bf16x8*)&Qf[16 * w + l15][kk * 32 + l4 * 8];

    // q.zp via extra MFMA column
    f32x4 p4 = z4;
    #pragma unroll
    for (int kk = 0; kk < 4; ++kk) p4 = MFMA(aq[kk], bz[kk], p4);

    // QK^T causal -> Ps (wave-local rows); in-reg masked rowsum
    float rs[4] = {0.f, 0.f, 0.f, 0.f};
    #pragma unroll
    for (int n2 = 0; n2 < 4; ++n2) {
        f32x4 p = z4;
        #pragma unroll
        for (int kk = 0; kk < 4; ++kk) {
            bf16x8 bk = *(const bf16x8*)&Kf[16 * n2 + l15][kk * 32 + l4 * 8];
            p = MFMA(aq[kk], bk, p);
        }
        int t2 = 16 * n2 + l15;
        #pragma unroll
        for (int j = 0; j < 4; ++j) {
            int t = 16 * w + l4 * 4 + j;
            float pm = (t2 <= t) ? p[j] : 0.f;
            Ps[t][t2] = f2b(pm);
            rs[j] += pm;
        }
    }
    // reduce rowsum across l15 (lane bits 0..3)
    #pragma unroll
    for (int off = 1; off < 16; off <<= 1) {
        #pragma unroll
        for (int j = 0; j < 4; ++j) rs[j] += __shfl_xor(rs[j], off);
    }
    if (l15 == 0) {
        #pragma unroll
        for (int j = 0; j < 4; ++j)
            den[16 * w + l4 * 4 + j] = rs[j] + p4[j] + 1e-6f;
    }
    // Ps rows + den entries for this wave are wave-local; no barrier needed

    // out half: e = 64h + 16n + l15, n = 0..3
    bf16x8 ap[2];
    #pragma unroll
    for (int kk = 0; kk < 2; ++kk)
        ap[kk] = *(const bf16x8*)&Ps[16 * w + l15][kk * 32 + l4 * 8];

    const short* Sp  = Sp_g + (size_t)c * DD * DD;
    const short* vTg = vT_g + (size_t)c * DD * CHK;
    f32x4 oacc[4];
    #pragma unroll
    for (int n = 0; n < 4; ++n) oacc[n] = z4;
    #pragma unroll
    for (int n = 0; n < 4; ++n) {
        int e = 64 * h + 16 * n + l15;
        #pragma unroll
        for (int kk = 0; kk < 4; ++kk) {
            bf16x8 bs = *(const bf16x8*)(Sp + e * DD + kk * 32 + l4 * 8);
            oacc[n] = MFMA(aq[kk], bs, oacc[n]);
        }
        #pragma unroll
        for (int kk = 0; kk < 2; ++kk) {
            bf16x8 bv = *(const bf16x8*)(vTg + e * CHK + kk * 32 + l4 * 8);
            oacc[n] = MFMA(ap[kk], bv, oacc[n]);
        }
    }

    float* oc = out + (size_t)c * CHK * DD;
    float invs[4];
    #pragma unroll
    for (int j = 0; j < 4; ++j) invs[j] = 1.0f / den[16 * w + l4 * 4 + j];
    #pragma unroll
    for (int n = 0; n < 4; ++n) {
        int e = 64 * h + 16 * n + l15;
        #pragma unroll
        for (int j = 0; j < 4; ++j) {
            int t = 16 * w + l4 * 4 + j;
            oc[t * DD + e] = oacc[n][j] * invs[j];
        }
    }
}

// ---------------------------------------------------------------------------
extern "C" void kernel_launch(void* const* d_in, const int* in_sizes, int n_in,
                              void* d_out, int out_size, void* d_ws, size_t ws_size,
                              hipStream_t stream) {
    const float* q  = (const float*)d_in[0];
    const float* k  = (const float*)d_in[1];
    const float* v  = (const float*)d_in[2];
    const float* W  = (const float*)d_in[3];
    const float* bi = (const float*)d_in[4];
    float* out = (float*)d_out;

    float* zc_g = (float*)d_ws;                         // 16384 f32
    float* zp_g = zc_g + (size_t)NCHKS * DD;            // 16384 f32
    short* Ss_g = (short*)(zp_g + (size_t)NCHKS * DD);  // 4 MB
    short* Sp_g = Ss_g + (size_t)NCHKS * DD * DD;       // 4 MB
    short* vT_g = Sp_g + (size_t)NCHKS * DD * DD;       // 2 MB
    short* Qf_g = vT_g + (size_t)NCHKS * DD * CHK;      // 2 MB
    short* Kf_g = Qf_g + (size_t)NCHKS * CHK * DD;      // 2 MB

    k1_chunk<<<2 * NCHKS, 256, 0, stream>>>(q, k, v, W, bi, Ss_g, zc_g, vT_g, Qf_g, Kf_g);
    k2_scan<<<512, 128, 0, stream>>>(Ss_g, zc_g, Sp_g, zp_g);
    k3_out<<<2 * NCHKS, 256, 0, stream>>>(Qf_g, Kf_g, Sp_g, zp_g, vT_g, out);
}